// Round 4
// baseline (582.381 us; speedup 1.0000x reference)
//
#include <hip/hip_runtime.h>
#include <hip/hip_bf16.h>
#include <hip/hip_fp16.h>

#define Bn 2
#define Tn 12
#define Hn 80
#define Wn 120
#define CIN 6
#define Fn 32
#define SITES (Hn * Wn)          // 9600
#define BH_ROW 296               // shorts per LDS weight row (288 + 8 pad)
#define RH_ROW 40                // shorts per rh LDS site (32 + 8 pad), 80 B
#define Z_ROW 33                 // floats per z LDS site (32 + 1 pad)

typedef __attribute__((ext_vector_type(8))) short short8;
typedef __attribute__((ext_vector_type(4))) float f32x4;

__device__ __forceinline__ short f2bf(float f) {
    union { __hip_bfloat16 h; short s; } u;
    u.h = __float2bfloat16(f);
    return u.s;
}
__device__ __forceinline__ float bf2f(short s) {
    union { float f; unsigned u; } u;
    u.u = ((unsigned)(unsigned short)s) << 16;
    return u.f;
}
__device__ __forceinline__ float fast_sigmoid(float v) { return 1.f / (1.f + __expf(-v)); }
__device__ __forceinline__ float fast_tanh(float v) {
    v = fminf(fmaxf(v, -15.f), 15.f);
    float e = __expf(2.f * v);
    return (e - 1.f) / (e + 1.f);
}

// ---- one-time weight pack ----
// wzrP: [2][64][288] (k = tap*32+ch)   whP: [2][32][288]
// wxP:  [2][96][96]  (k = chunk*32 + qq*8 + j ; tap = chunk*4+qq, ci = j, zero-padded)
__global__ __launch_bounds__(256) void pack_weights(
    const float* __restrict__ Wzr_f, const float* __restrict__ Wzr_b,
    const float* __restrict__ Wh_f,  const float* __restrict__ Wh_b,
    const float* __restrict__ Wx_f,  const float* __restrict__ Wx_b,
    short* __restrict__ wzrP, short* __restrict__ whP, short* __restrict__ wxP)
{
    int i = blockIdx.x * 256 + threadIdx.x;
    const int SZR = 2 * 64 * 288;
    const int SWH = 2 * 32 * 288;
    const int SWX = 2 * 96 * 96;
    if (i < SZR) {
        int dir = i / (64 * 288); int r = i % (64 * 288);
        int nn = r / 288, k = r % 288;
        const float* W = dir ? Wzr_b : Wzr_f;      // [tap][ci32][64]
        wzrP[i] = f2bf(W[k * 64 + nn]);
    } else if (i < SZR + SWH) {
        int j = i - SZR;
        int dir = j / (32 * 288); int r = j % (32 * 288);
        int nn = r / 288, k = r % 288;
        const float* W = dir ? Wh_b : Wh_f;        // [tap][ci32][32]
        whP[j] = f2bf(W[k * 32 + nn]);
    } else if (i < SZR + SWH + SWX) {
        int j = i - SZR - SWH;
        int dir = j / (96 * 96); int r = j % (96 * 96);
        int col = r / 96, k = r % 96;
        int chunk = k / 32, qq = (k % 32) / 8, jj = k % 8;
        int tap = chunk * 4 + qq;
        const float* W = dir ? Wx_b : Wx_f;        // [tap][ci6][96]
        wxP[j] = (tap < 9 && jj < 6) ? f2bf(W[(tap * CIN + jj) * 96 + col]) : (short)0;
    }
}

// ---- xc precompute: xc = conv(x, Wx) + b for all 48 (dir,b,t) slabs ----
// out: xcg fp16 [slab][site][64], xch fp16 [slab][site][32]
// grid: 7200 blocks (48 slabs x 150 tile-quads), 256 thr (4 waves, 1 site-tile each)
__global__ __launch_bounds__(256) void xconv_kernel(
    const float* __restrict__ x,
    const float* __restrict__ b_f, const float* __restrict__ b_b,
    const short* __restrict__ wxP,
    __half* __restrict__ xcg, __half* __restrict__ xch)
{
    __shared__ short lds[96 * 104];
    int tid = threadIdx.x;
    int bid = blockIdx.x;
    int slab = bid / 150;
    int tq   = bid % 150;
    int dir  = slab / 24;
    int rem  = slab % 24;
    int b    = rem / 12;
    int t    = rem % 12;

    const short* src = wxP + dir * 96 * 96;
    for (int i = tid; i < 96 * 12; i += 256) {
        int row = i / 12, c = i % 12;
        *(uint4*)&lds[row * 104 + c * 8] = *(const uint4*)&src[row * 96 + c * 8];
    }
    __syncthreads();

    int wid = tid >> 6, lane = tid & 63;
    int n = lane & 15, q = lane >> 4;
    int tt = tq * 4 + wid;             // 0..599
    int site0 = tt * 16;
    int site_l = site0 + n;
    int y  = site_l / Wn;
    int px = site_l % Wn;

    const float* xslab = x + (size_t)((b * Tn + t) * SITES) * CIN;
    const float* bias = dir ? b_b : b_f;

    f32x4 acc[6];
    #pragma unroll
    for (int nt = 0; nt < 6; nt++) acc[nt] = (f32x4)0.f;

    #pragma unroll
    for (int c = 0; c < 3; c++) {
        int tap = c * 4 + q;
        short8 a = (short8)(short)0;
        if (tap < 9) {
            int iy = y + tap / 3 - 1;
            int ix = px + tap % 3 - 1;
            if (iy >= 0 && iy < Hn && ix >= 0 && ix < Wn) {
                const float* xp = xslab + (size_t)(iy * Wn + ix) * CIN;
                a[0] = f2bf(xp[0]); a[1] = f2bf(xp[1]); a[2] = f2bf(xp[2]);
                a[3] = f2bf(xp[3]); a[4] = f2bf(xp[4]); a[5] = f2bf(xp[5]);
            }
        }
        #pragma unroll
        for (int nt = 0; nt < 6; nt++) {
            short8 bb = *(const short8*)&lds[(nt * 16 + n) * 104 + c * 32 + q * 8];
            acc[nt] = __builtin_amdgcn_mfma_f32_16x16x32_bf16(a, bb, acc[nt], 0, 0, 0);
        }
    }

    __half* og = xcg + (size_t)slab * SITES * 64;
    __half* oh = xch + (size_t)slab * SITES * 32;
    #pragma unroll
    for (int nt = 0; nt < 6; nt++) {
        int col = nt * 16 + n;
        float bv = bias[col];
        #pragma unroll
        for (int r = 0; r < 4; r++) {
            int site = site0 + q * 4 + r;
            float v = acc[nt][r] + bv;
            if (nt < 4) og[(size_t)site * 64 + col] = __float2half(v);
            else        oh[(size_t)site * 32 + (col - 64)] = __float2half(v);
        }
    }
}

// ---- fused GRU step: gates (with 1-px halo) + candidate + update, one kernel ----
// grid: 640 = dir(2) x b(2) x yb(20) x seg(8); 256 thr = 4 waves
__global__ __launch_bounds__(256) void fused_step(
    const __half* __restrict__ xcg, const __half* __restrict__ xch,
    const short* __restrict__ wzrP, const short* __restrict__ whP,
    const float* __restrict__ hprevf, float* __restrict__ hcurf,
    const short* __restrict__ hb_prev, short* __restrict__ hb_cur,
    float* __restrict__ out, int s)
{
    __shared__ short wlds[64 * BH_ROW];              // Wzr, then re-staged Wh
    __shared__ short rh_lds[108 * RH_ROW];           // r*h bf16, halo 6x18
    __shared__ float z_lds[108 * Z_ROW];             // z fp32, halo 6x18

    int tid = threadIdx.x;
    int bid = blockIdx.x;
    int seg = bid & 7;
    int t1  = bid >> 3;
    int yb  = t1 % 20;
    int t2  = t1 / 20;
    int b   = t2 & 1;
    int dir = t2 >> 1;
    int y0  = yb * 4;
    int x0  = seg * 16;
    int t   = dir ? (Tn - 1 - s) : s;
    int slab  = (dir * Bn + b) * Tn + t;             // xc slab
    int pslab = (dir * Bn + b) * SITES;              // h field base (sites)

    // stage Wzr (64 x 288)
    {
        const short* src = wzrP + dir * 64 * 288;
        for (int i = tid; i < 64 * 36; i += 256) {
            int row = i / 36, c = i % 36;
            *(uint4*)&wlds[row * BH_ROW + c * 8] = *(const uint4*)&src[row * 288 + c * 8];
        }
    }
    __syncthreads();

    int wid = tid >> 6, lane = tid & 63;
    int n = lane & 15, q = lane >> 4;
    int q8 = q * 8;

    const short* hbp = hb_prev + (size_t)pslab * Fn;
    const __half* xg = xcg + (size_t)slab * SITES * 64;

    // ---- phase 1: z,r over halo sites (7 tiles of 16 over 108 sites) ----
    for (int tt = wid; tt < 7; tt += 4) {
        int site_l = tt * 16 + n;
        int hr = site_l / 18, hc = site_l % 18;
        int sy = y0 - 1 + hr, sx = x0 - 1 + hc;
        bool site_ok = site_l < 108;

        f32x4 acc[4];
        #pragma unroll
        for (int nt = 0; nt < 4; nt++) acc[nt] = (f32x4)0.f;

        if (s > 0) {
            #pragma unroll
            for (int ky = 0; ky < 3; ky++) {
                #pragma unroll
                for (int kx = 0; kx < 3; kx++) {
                    int tap = ky * 3 + kx;
                    int iy = sy + ky - 1, ix = sx + kx - 1;
                    bool ok = site_ok && iy >= 0 && iy < Hn && ix >= 0 && ix < Wn;
                    short8 ah = (short8)(short)0;
                    if (ok) ah = *(const short8*)&hbp[(size_t)(iy * Wn + ix) * Fn + q8];
                    #pragma unroll
                    for (int nt = 0; nt < 4; nt++) {
                        short8 bh = *(const short8*)&wlds[(nt * 16 + n) * BH_ROW + tap * 32 + q8];
                        acc[nt] = __builtin_amdgcn_mfma_f32_16x16x32_bf16(ah, bh, acc[nt], 0, 0, 0);
                    }
                }
            }
        }

        // epilogue: C row = q*4+r (site within tile), col = nt*16+n
        #pragma unroll
        for (int nt = 0; nt < 4; nt++) {
            int col = nt * 16 + n;
            #pragma unroll
            for (int r = 0; r < 4; r++) {
                int site_e = tt * 16 + q * 4 + r;
                if (site_e >= 108) continue;
                int ehr = site_e / 18, ehc = site_e % 18;
                int ey = y0 - 1 + ehr, ex = x0 - 1 + ehc;
                bool img = (ey >= 0 && ey < Hn && ex >= 0 && ex < Wn);
                if (nt < 2) {
                    if (img) {
                        float xv = __half2float(xg[(size_t)(ey * Wn + ex) * 64 + col]);
                        z_lds[site_e * Z_ROW + col] = fast_sigmoid(acc[nt][r] + xv);
                    }
                } else {
                    int ch = col - 32;
                    float rhv = 0.f;
                    if (img) {
                        float xv = __half2float(xg[(size_t)(ey * Wn + ex) * 64 + col]);
                        float rv = fast_sigmoid(acc[nt][r] + xv);
                        float hp = (s > 0) ? hprevf[(size_t)(pslab + ey * Wn + ex) * Fn + ch] : 0.f;
                        rhv = rv * hp;
                    }
                    rh_lds[site_e * RH_ROW + ch] = f2bf(rhv);
                }
            }
        }
    }
    __syncthreads();

    // re-stage Wh (32 x 288) over the Wzr region
    {
        const short* src = whP + dir * 32 * 288;
        for (int i = tid; i < 32 * 36; i += 256) {
            int row = i / 36, c = i % 36;
            *(uint4*)&wlds[row * BH_ROW + c * 8] = *(const uint4*)&src[row * 288 + c * 8];
        }
    }
    __syncthreads();

    // ---- phase 2: candidate conv over LDS rh; wave wid -> interior row y0+wid ----
    int y = y0 + wid;
    f32x4 acc2[2];
    acc2[0] = (f32x4)0.f; acc2[1] = (f32x4)0.f;
    #pragma unroll
    for (int ky = 0; ky < 3; ky++) {
        #pragma unroll
        for (int kx = 0; kx < 3; kx++) {
            int tap = ky * 3 + kx;
            short8 ar = *(const short8*)&rh_lds[((wid + ky) * 18 + (n + kx)) * RH_ROW + q8];
            #pragma unroll
            for (int nt = 0; nt < 2; nt++) {
                short8 bh = *(const short8*)&wlds[(nt * 16 + n) * BH_ROW + tap * 32 + q8];
                acc2[nt] = __builtin_amdgcn_mfma_f32_16x16x32_bf16(ar, bh, acc2[nt], 0, 0, 0);
            }
        }
    }

    // ---- final epilogue: h = z*h_prev + (1-z)*tanh(xch + conv(rh)) ----
    const __half* xh = xch + (size_t)slab * SITES * 32;
    #pragma unroll
    for (int nt = 0; nt < 2; nt++) {
        int ch = nt * 16 + n;
        #pragma unroll
        for (int r = 0; r < 4; r++) {
            int px = x0 + q * 4 + r;
            if (px >= Wn) continue;
            int sidx = y * Wn + px;
            float xv = __half2float(xh[(size_t)sidx * 32 + ch]);
            float hh = fast_tanh(acc2[nt][r] + xv);
            float z  = z_lds[((wid + 1) * 18 + (q * 4 + r + 1)) * Z_ROW + ch];
            float hp = (s > 0) ? hprevf[(size_t)(pslab + sidx) * Fn + ch] : 0.f;
            float hn = z * hp + (1.f - z) * hh;
            hcurf[(size_t)(pslab + sidx) * Fn + ch] = hn;
            hb_cur[(size_t)(pslab + sidx) * Fn + ch] = f2bf(hn);
            out[((size_t)((b * Tn + t) * SITES) + sidx) * 64 + dir * Fn + ch] = hn;
        }
    }
}

extern "C" void kernel_launch(void* const* d_in, const int* in_sizes, int n_in,
                              void* d_out, int out_size, void* d_ws, size_t ws_size,
                              hipStream_t stream)
{
    const float* x     = (const float*)d_in[0];
    const float* Wx_f  = (const float*)d_in[1];
    const float* b_f   = (const float*)d_in[2];
    const float* Wzr_f = (const float*)d_in[3];
    const float* Wh_f  = (const float*)d_in[4];
    const float* Wx_b  = (const float*)d_in[5];
    const float* b_b   = (const float*)d_in[6];
    const float* Wzr_b = (const float*)d_in[7];
    const float* Wh_b  = (const float*)d_in[8];
    float* out = (float*)d_out;

    const size_t HS = (size_t)2 * Bn * SITES * Fn;   // 1,228,800
    char* w = (char*)d_ws;
    float*  h0f  = (float*)w;  w += HS * 4;
    float*  h1f  = (float*)w;  w += HS * 4;
    short*  hb0  = (short*)w;  w += HS * 2;
    short*  hb1  = (short*)w;  w += HS * 2;
    __half* xcg  = (__half*)w; w += (size_t)48 * SITES * 64 * 2;
    __half* xch  = (__half*)w; w += (size_t)48 * SITES * 32 * 2;
    short*  wzrP = (short*)w;  w += 2 * 64 * 288 * 2;
    short*  whP  = (short*)w;  w += 2 * 32 * 288 * 2;
    short*  wxP  = (short*)w;  w += 2 * 96 * 96 * 2;
    // total ~103 MB

    pack_weights<<<288, 256, 0, stream>>>(Wzr_f, Wzr_b, Wh_f, Wh_b, Wx_f, Wx_b,
                                          wzrP, whP, wxP);
    xconv_kernel<<<7200, 256, 0, stream>>>(x, b_f, b_b, wxP, xcg, xch);

    for (int s = 0; s < Tn; s++) {
        float* hprev = (s & 1) ? h0f : h1f;
        float* hcur  = (s & 1) ? h1f : h0f;
        short* hbp   = (s & 1) ? hb0 : hb1;
        short* hbc   = (s & 1) ? hb1 : hb0;
        fused_step<<<640, 256, 0, stream>>>(xcg, xch, wzrP, whP,
                                            hprev, hcur, hbp, hbc, out, s);
    }
}

// Round 5
// 365.479 us; speedup vs baseline: 1.5935x; 1.5935x over previous
//
#include <hip/hip_runtime.h>
#include <hip/hip_bf16.h>
#include <hip/hip_fp16.h>

#define Bn 2
#define Tn 12
#define Hn 80
#define Wn 120
#define CIN 6
#define Fn 32
#define SITES (Hn * Wn)      // 9600
#define TILES 600            // 16-site flat tiles per field image
#define HSZ 1228800          // 4 fields * 9600 sites * 32 ch

typedef __attribute__((ext_vector_type(8))) short short8;
typedef __attribute__((ext_vector_type(4))) float f32x4;

__device__ __forceinline__ short f2bf(float f) {
    union { __hip_bfloat16 h; short s; } u;
    u.h = __float2bfloat16(f);
    return u.s;
}
__device__ __forceinline__ float fast_sigmoid(float v) { return 1.f / (1.f + __expf(-v)); }
__device__ __forceinline__ float fast_tanh(float v) {
    v = fminf(fmaxf(v, -15.f), 15.f);
    float e = __expf(2.f * v);
    return (e - 1.f) / (e + 1.f);
}

// ---- one-time weight pack ----
// wzrP: [2][64][288] (k = tap*32+ch)   whP: [2][32][288]   wxP: [2][96][96]
__global__ __launch_bounds__(256) void pack_weights(
    const float* __restrict__ Wzr_f, const float* __restrict__ Wzr_b,
    const float* __restrict__ Wh_f,  const float* __restrict__ Wh_b,
    const float* __restrict__ Wx_f,  const float* __restrict__ Wx_b,
    short* __restrict__ wzrP, short* __restrict__ whP, short* __restrict__ wxP)
{
    int i = blockIdx.x * 256 + threadIdx.x;
    const int SZR = 2 * 64 * 288;
    const int SWH = 2 * 32 * 288;
    const int SWX = 2 * 96 * 96;
    if (i < SZR) {
        int dir = i / (64 * 288); int r = i % (64 * 288);
        int nn = r / 288, k = r % 288;
        const float* W = dir ? Wzr_b : Wzr_f;      // [tap][ci32][64]
        wzrP[i] = f2bf(W[k * 64 + nn]);
    } else if (i < SZR + SWH) {
        int j = i - SZR;
        int dir = j / (32 * 288); int r = j % (32 * 288);
        int nn = r / 288, k = r % 288;
        const float* W = dir ? Wh_b : Wh_f;        // [tap][ci32][32]
        whP[j] = f2bf(W[k * 32 + nn]);
    } else if (i < SZR + SWH + SWX) {
        int j = i - SZR - SWH;
        int dir = j / (96 * 96); int r = j % (96 * 96);
        int col = r / 96, k = r % 96;
        int chunk = k / 32, qq = (k % 32) / 8, jj = k % 8;
        int tap = chunk * 4 + qq;
        const float* W = dir ? Wx_b : Wx_f;        // [tap][ci6][96]
        wxP[j] = (tap < 9 && jj < 6) ? f2bf(W[(tap * CIN + jj) * 96 + col]) : (short)0;
    }
}

// ---- zero h state (slot 1 = prev at s==0) ----
__global__ __launch_bounds__(256) void zero_init(float* __restrict__ hC1, short* __restrict__ hb1)
{
    int i = blockIdx.x * 256 + threadIdx.x;
    if (i < HSZ / 4) ((f32x4*)hC1)[i] = (f32x4)0.f;
    int j = i - HSZ / 4;
    if (j >= 0 && j < HSZ / 8) ((short8*)hb1)[j] = (short8)(short)0;
}

// ---- xc precompute: xc = conv(x, Wx) + b, stored in MFMA C-layout fp16 ----
// xcC: [slab48][tile600][nt6][lane64][r4]   (nt 0..3 = z|r gate cols, 4..5 = candidate)
__global__ __launch_bounds__(64) void xconv_kernel(
    const float* __restrict__ x,
    const float* __restrict__ b_f, const float* __restrict__ b_b,
    const short* __restrict__ wxP, __half* __restrict__ xcC)
{
    int bid = blockIdx.x;              // 0..28799
    int slab = bid / TILES;            // field*12 + t
    int tt   = bid % TILES;
    int dir  = slab / 24;
    int b    = (slab % 24) / 12;
    int t    = slab % 12;

    int lane = threadIdx.x;
    int n = lane & 15, q = lane >> 4;
    int site = tt * 16 + n;
    int y = site / Wn, px = site % Wn;

    const float* xs = x + (size_t)((b * Tn + t) * SITES) * CIN;
    const short* wb = wxP + dir * 96 * 96;

    f32x4 acc[6];
    #pragma unroll
    for (int nt = 0; nt < 6; nt++) acc[nt] = (f32x4)0.f;

    #pragma unroll
    for (int chunk = 0; chunk < 3; chunk++) {
        int tap = chunk * 4 + q;
        short8 a = (short8)(short)0;
        if (tap < 9) {
            int iy = y + tap / 3 - 1;
            int ix = px + tap % 3 - 1;
            if (iy >= 0 && iy < Hn && ix >= 0 && ix < Wn) {
                const float* xp = xs + (size_t)(iy * Wn + ix) * CIN;
                a[0] = f2bf(xp[0]); a[1] = f2bf(xp[1]); a[2] = f2bf(xp[2]);
                a[3] = f2bf(xp[3]); a[4] = f2bf(xp[4]); a[5] = f2bf(xp[5]);
            }
        }
        #pragma unroll
        for (int nt = 0; nt < 6; nt++) {
            short8 bfr = *(const short8*)&wb[(nt * 16 + n) * 96 + chunk * 32 + q * 8];
            acc[nt] = __builtin_amdgcn_mfma_f32_16x16x32_bf16(a, bfr, acc[nt], 0, 0, 0);
        }
    }

    const float* bias = dir ? b_b : b_f;
    __half* o = xcC + (size_t)(slab * TILES + tt) * 1536;
    #pragma unroll
    for (int nt = 0; nt < 6; nt++) {
        float bv = bias[nt * 16 + n];
        __half hv[4];
        #pragma unroll
        for (int r = 0; r < 4; r++) hv[r] = __float2half(acc[nt][r] + bv);
        *(uint2*)&o[(nt * 64 + lane) * 4] = *(uint2*)hv;
    }
}

// ---- gates: z (C-layout fp32) and r*h (bf16 site-layout) ----
// grid 2400 x 64thr; one wave = one 16-site tile, 64 gate cols
__global__ __launch_bounds__(64) void gates_mfma(
    const __half* __restrict__ xcC, const short* __restrict__ wzrP,
    const short* __restrict__ hb_prev,   // [field][site][32] bf16
    const float* __restrict__ hC_prev,   // [field][tile][ntc2][lane][4] fp32
    float* __restrict__ zC,              // [field][tile][nt2][lane][4] fp32
    short* __restrict__ rh, int s)
{
    int bid = blockIdx.x;
    int field = bid / TILES;
    int tt    = bid % TILES;
    int dir = field >> 1;
    int t = dir ? (Tn - 1 - s) : s;
    int slab = field * Tn + t;

    int lane = threadIdx.x;
    int n = lane & 15, q = lane >> 4, q8 = q * 8;
    int site = tt * 16 + n;
    int y = site / Wn, px = site % Wn;

    const short* hbp = hb_prev + (size_t)field * SITES * Fn;
    const short* wb  = wzrP + dir * 64 * 288;

    f32x4 acc[4];
    #pragma unroll
    for (int nt = 0; nt < 4; nt++) acc[nt] = (f32x4)0.f;

    #pragma unroll
    for (int ky = 0; ky < 3; ky++) {
        int iy = y + ky - 1;
        bool rowok = (iy >= 0 && iy < Hn);
        #pragma unroll
        for (int kx = 0; kx < 3; kx++) {
            int tap = ky * 3 + kx;
            int ix = px + kx - 1;
            bool ok = rowok && ix >= 0 && ix < Wn;
            short8 ah = (short8)(short)0;
            if (ok) ah = *(const short8*)&hbp[(size_t)(iy * Wn + ix) * Fn + q8];
            #pragma unroll
            for (int nt = 0; nt < 4; nt++) {
                short8 bh = *(const short8*)&wb[(nt * 16 + n) * 288 + tap * 32 + q8];
                acc[nt] = __builtin_amdgcn_mfma_f32_16x16x32_bf16(ah, bh, acc[nt], 0, 0, 0);
            }
        }
    }

    const __half* xg = xcC + (size_t)(slab * TILES + tt) * 1536;
    short* rhs = rh + (size_t)field * SITES * Fn;
    #pragma unroll
    for (int nt = 0; nt < 4; nt++) {
        __half hv[4];
        *(uint2*)hv = *(const uint2*)&xg[(nt * 64 + lane) * 4];
        if (nt < 2) {
            f32x4 z;
            #pragma unroll
            for (int r = 0; r < 4; r++) z[r] = fast_sigmoid(acc[nt][r] + __half2float(hv[r]));
            *(f32x4*)&zC[((size_t)(field * TILES + tt) * 2 + nt) * 256 + lane * 4] = z;
        } else {
            int ntc = nt - 2;
            f32x4 hp = *(const f32x4*)&hC_prev[((size_t)(field * TILES + tt) * 2 + ntc) * 256 + lane * 4];
            #pragma unroll
            for (int r = 0; r < 4; r++) {
                float rv = fast_sigmoid(acc[nt][r] + __half2float(hv[r]));
                int site_e = tt * 16 + q * 4 + r;
                rhs[(size_t)site_e * Fn + ntc * 16 + n] = f2bf(rv * hp[r]);
            }
        }
    }
}

// ---- update: candidate conv over rh, then h = z*h_prev + (1-z)*tanh(.) ----
__global__ __launch_bounds__(64) void update_mfma(
    const __half* __restrict__ xcC, const short* __restrict__ whP,
    const short* __restrict__ rh,
    const float* __restrict__ hC_prev, const float* __restrict__ zC,
    float* __restrict__ hC_cur, short* __restrict__ hb_cur,
    float* __restrict__ out, int s)
{
    int bid = blockIdx.x;
    int field = bid / TILES;
    int tt    = bid % TILES;
    int dir = field >> 1;
    int b   = field & 1;
    int t = dir ? (Tn - 1 - s) : s;
    int slab = field * Tn + t;

    int lane = threadIdx.x;
    int n = lane & 15, q = lane >> 4, q8 = q * 8;
    int site = tt * 16 + n;
    int y = site / Wn, px = site % Wn;

    const short* rhs = rh + (size_t)field * SITES * Fn;
    const short* wb  = whP + dir * 32 * 288;

    f32x4 acc[2];
    acc[0] = (f32x4)0.f; acc[1] = (f32x4)0.f;

    #pragma unroll
    for (int ky = 0; ky < 3; ky++) {
        int iy = y + ky - 1;
        bool rowok = (iy >= 0 && iy < Hn);
        #pragma unroll
        for (int kx = 0; kx < 3; kx++) {
            int tap = ky * 3 + kx;
            int ix = px + kx - 1;
            bool ok = rowok && ix >= 0 && ix < Wn;
            short8 ar = (short8)(short)0;
            if (ok) ar = *(const short8*)&rhs[(size_t)(iy * Wn + ix) * Fn + q8];
            #pragma unroll
            for (int ntc = 0; ntc < 2; ntc++) {
                short8 bh = *(const short8*)&wb[(ntc * 16 + n) * 288 + tap * 32 + q8];
                acc[ntc] = __builtin_amdgcn_mfma_f32_16x16x32_bf16(ar, bh, acc[ntc], 0, 0, 0);
            }
        }
    }

    const __half* xg = xcC + (size_t)(slab * TILES + tt) * 1536;
    short* hbc = hb_cur + (size_t)field * SITES * Fn;
    #pragma unroll
    for (int ntc = 0; ntc < 2; ntc++) {
        __half hv[4];
        *(uint2*)hv = *(const uint2*)&xg[((4 + ntc) * 64 + lane) * 4];
        size_t cofs = ((size_t)(field * TILES + tt) * 2 + ntc) * 256 + lane * 4;
        f32x4 z  = *(const f32x4*)&zC[cofs];
        f32x4 hp = *(const f32x4*)&hC_prev[cofs];
        f32x4 hn;
        #pragma unroll
        for (int r = 0; r < 4; r++) {
            float hh = fast_tanh(acc[ntc][r] + __half2float(hv[r]));
            hn[r] = z[r] * hp[r] + (1.f - z[r]) * hh;
        }
        *(f32x4*)&hC_cur[cofs] = hn;
        #pragma unroll
        for (int r = 0; r < 4; r++) {
            int site_e = tt * 16 + q * 4 + r;
            int ch = ntc * 16 + n;
            hbc[(size_t)site_e * Fn + ch] = f2bf(hn[r]);
            out[((size_t)((b * Tn + t) * SITES) + site_e) * 64 + dir * Fn + ch] = hn[r];
        }
    }
}

extern "C" void kernel_launch(void* const* d_in, const int* in_sizes, int n_in,
                              void* d_out, int out_size, void* d_ws, size_t ws_size,
                              hipStream_t stream)
{
    const float* x     = (const float*)d_in[0];
    const float* Wx_f  = (const float*)d_in[1];
    const float* b_f   = (const float*)d_in[2];
    const float* Wzr_f = (const float*)d_in[3];
    const float* Wh_f  = (const float*)d_in[4];
    const float* Wx_b  = (const float*)d_in[5];
    const float* b_b   = (const float*)d_in[6];
    const float* Wzr_b = (const float*)d_in[7];
    const float* Wh_b  = (const float*)d_in[8];
    float* out = (float*)d_out;

    char* w = (char*)d_ws;
    float*  hC0  = (float*)w;  w += (size_t)HSZ * 4;
    float*  hC1  = (float*)w;  w += (size_t)HSZ * 4;
    float*  zC   = (float*)w;  w += (size_t)HSZ * 4;
    short*  hb0  = (short*)w;  w += (size_t)HSZ * 2;
    short*  hb1  = (short*)w;  w += (size_t)HSZ * 2;
    short*  rh   = (short*)w;  w += (size_t)HSZ * 2;
    __half* xcC  = (__half*)w; w += (size_t)48 * TILES * 1536 * 2;   // 88.5 MB
    short*  wzrP = (short*)w;  w += 2 * 64 * 288 * 2;
    short*  whP  = (short*)w;  w += 2 * 32 * 288 * 2;
    short*  wxP  = (short*)w;  w += 2 * 96 * 96 * 2;
    // total ~111 MB

    pack_weights<<<288, 256, 0, stream>>>(Wzr_f, Wzr_b, Wh_f, Wh_b, Wx_f, Wx_b,
                                          wzrP, whP, wxP);
    xconv_kernel<<<48 * TILES, 64, 0, stream>>>(x, b_f, b_b, wxP, xcC);
    zero_init<<<1800, 256, 0, stream>>>(hC1, hb1);

    for (int s = 0; s < Tn; s++) {
        int cur = s & 1, prev = 1 - cur;
        float* hCp = prev ? hC1 : hC0;
        float* hCc = cur  ? hC1 : hC0;
        short* hbp = prev ? hb1 : hb0;
        short* hbc = cur  ? hb1 : hb0;
        gates_mfma<<<2400, 64, 0, stream>>>(xcC, wzrP, hbp, hCp, zC, rh, s);
        update_mfma<<<2400, 64, 0, stream>>>(xcC, whP, rh, hCp, zC, hCc, hbc, out, s);
    }
}

// Round 6
// 363.308 us; speedup vs baseline: 1.6030x; 1.0060x over previous
//
#include <hip/hip_runtime.h>
#include <hip/hip_bf16.h>

#define Bn 2
#define Tn 12
#define Hn 80
#define Wn 120
#define CIN 6
#define Fn 32
#define SITES (Hn * Wn)      // 9600
#define TILES 600            // 16-site flat tiles per field image
#define HSZ 1228800          // 4 fields * 9600 sites * 32 ch
#define W_ROW 392            // shorts per LDS weight row: 384 data + 8 pad (16B-aligned, conflict-free)

typedef __attribute__((ext_vector_type(8))) short short8;
typedef __attribute__((ext_vector_type(4))) float f32x4;

__device__ __forceinline__ short f2bf(float f) {
    union { __hip_bfloat16 h; short s; } u;
    u.h = __float2bfloat16(f);
    return u.s;
}
__device__ __forceinline__ float fast_sigmoid(float v) { return 1.f / (1.f + __expf(-v)); }
__device__ __forceinline__ float fast_tanh(float v) {
    v = fminf(fmaxf(v, -15.f), 15.f);
    float e = __expf(2.f * v);
    return (e - 1.f) / (e + 1.f);
}

// ---- one prologue kernel: pack weights (transposed bf16) + pack x to padded bf16x8 ----
// wzrP: [2][64][288] (k = tap*32+ch)   whP: [2][32][288]
// wxP:  [2][96][96]  (k = chunk*32+qq*8+jj ; tap = chunk*4+qq, ci = jj, zero-padded)
// xb8:  [Bn*Tn*SITES][8] bf16 (ch 6,7 = 0)
__global__ __launch_bounds__(256) void prep_kernel(
    const float* __restrict__ Wzr_f, const float* __restrict__ Wzr_b,
    const float* __restrict__ Wh_f,  const float* __restrict__ Wh_b,
    const float* __restrict__ Wx_f,  const float* __restrict__ Wx_b,
    const float* __restrict__ x,
    short* __restrict__ wzrP, short* __restrict__ whP, short* __restrict__ wxP,
    short* __restrict__ xb8)
{
    int i = blockIdx.x * 256 + threadIdx.x;
    const int SZR = 2 * 64 * 288;
    const int SWH = 2 * 32 * 288;
    const int SWX = 2 * 96 * 96;
    const int NPX = Bn * Tn * SITES;       // 230400
    if (i < SZR) {
        int dir = i / (64 * 288); int r = i % (64 * 288);
        int nn = r / 288, k = r % 288;
        const float* W = dir ? Wzr_b : Wzr_f;      // [tap][ci32][64]
        wzrP[i] = f2bf(W[k * 64 + nn]);
    } else if (i < SZR + SWH) {
        int j = i - SZR;
        int dir = j / (32 * 288); int r = j % (32 * 288);
        int nn = r / 288, k = r % 288;
        const float* W = dir ? Wh_b : Wh_f;        // [tap][ci32][32]
        whP[j] = f2bf(W[k * 32 + nn]);
    } else if (i < SZR + SWH + SWX) {
        int j = i - SZR - SWH;
        int dir = j / (96 * 96); int r = j % (96 * 96);
        int col = r / 96, k = r % 96;
        int chunk = k / 32, qq = (k % 32) / 8, jj = k % 8;
        int tap = chunk * 4 + qq;
        const float* W = dir ? Wx_b : Wx_f;        // [tap][ci6][96]
        wxP[j] = (tap < 9 && jj < 6) ? f2bf(W[(tap * CIN + jj) * 96 + col]) : (short)0;
    } else {
        int p = i - SZR - SWH - SWX;
        if (p < NPX) {
            const float* xp = x + (size_t)p * CIN;
            short v[8];
            #pragma unroll
            for (int c = 0; c < CIN; c++) v[c] = f2bf(xp[c]);
            v[6] = 0; v[7] = 0;
            *(short8*)&xb8[(size_t)p * 8] = *(short8*)v;
        }
    }
}

// ---- gates: z (C-layout fp32) and r*h (bf16 site-layout) ----
// grid 600 = field(4) x tb(150); 256 thr = 4 waves, wave -> tile tb*4+wid
__global__ __launch_bounds__(256, 3) void gates_mfma(
    const short* __restrict__ xb8, const short* __restrict__ wzrP,
    const short* __restrict__ wxP,
    const float* __restrict__ b_f, const float* __restrict__ b_b,
    const short* __restrict__ hb_prev,   // [field][site][32] bf16
    const float* __restrict__ hC_prev,   // [field][tile][ntc2][lane][4] fp32
    float* __restrict__ zC,              // [field][tile][nt2][lane][4] fp32
    short* __restrict__ rh, int s)
{
    __shared__ short wl[64 * W_ROW];     // rows: [0,288)=Wzr, [288,384)=Wx cols 0..63
    int tid = threadIdx.x;
    int bid = blockIdx.x;
    int field = bid / 150;
    int tb    = bid % 150;
    int dir = field >> 1;
    int b   = field & 1;
    int t = dir ? (Tn - 1 - s) : s;

    {
        const short* wz = wzrP + dir * 64 * 288;
        const short* wx = wxP + dir * 96 * 96;
        for (int i = tid; i < 64 * 48; i += 256) {
            int row = i / 48, c = i % 48;
            uint4 v = (c < 36) ? *(const uint4*)&wz[row * 288 + c * 8]
                               : *(const uint4*)&wx[row * 96 + (c - 36) * 8];
            *(uint4*)&wl[row * W_ROW + c * 8] = v;
        }
    }
    __syncthreads();

    int wid = tid >> 6, lane = tid & 63;
    int n = lane & 15, q = lane >> 4, q8 = q * 8;
    int tt = tb * 4 + wid;
    int site = tt * 16 + n;
    int y = site / Wn, px = site % Wn;

    const short* hbp = hb_prev + (size_t)field * SITES * Fn;
    const short* xs  = xb8 + (size_t)((b * Tn + t) * SITES) * 8;
    const float* bias = dir ? b_b : b_f;

    f32x4 acc[4];
    #pragma unroll
    for (int nt = 0; nt < 4; nt++) acc[nt] = (f32x4)(bias[nt * 16 + n]);

    // ---- x chunks: 3 x K=32, tap = chunk*4+q ----
    #pragma unroll
    for (int c = 0; c < 3; c++) {
        int tap = c * 4 + q;
        short8 a = (short8)(short)0;
        if (tap < 9) {
            int iy = y + tap / 3 - 1;
            int ix = px + tap % 3 - 1;
            if (iy >= 0 && iy < Hn && ix >= 0 && ix < Wn)
                a = *(const short8*)&xs[(size_t)(iy * Wn + ix) * 8];
        }
        #pragma unroll
        for (int nt = 0; nt < 4; nt++) {
            short8 bf = *(const short8*)&wl[(nt * 16 + n) * W_ROW + 288 + c * 32 + q8];
            acc[nt] = __builtin_amdgcn_mfma_f32_16x16x32_bf16(a, bf, acc[nt], 0, 0, 0);
        }
    }

    // ---- h chunks: 9 taps x K=32 ----
    if (s > 0) {
        #pragma unroll
        for (int ky = 0; ky < 3; ky++) {
            int iy = y + ky - 1;
            bool rowok = (iy >= 0 && iy < Hn);
            #pragma unroll
            for (int kx = 0; kx < 3; kx++) {
                int tap = ky * 3 + kx;
                int ix = px + kx - 1;
                bool ok = rowok && ix >= 0 && ix < Wn;
                short8 ah = (short8)(short)0;
                if (ok) ah = *(const short8*)&hbp[(size_t)(iy * Wn + ix) * Fn + q8];
                #pragma unroll
                for (int nt = 0; nt < 4; nt++) {
                    short8 bh = *(const short8*)&wl[(nt * 16 + n) * W_ROW + tap * 32 + q8];
                    acc[nt] = __builtin_amdgcn_mfma_f32_16x16x32_bf16(ah, bh, acc[nt], 0, 0, 0);
                }
            }
        }
    }

    short* rhs = rh + (size_t)field * SITES * Fn;
    #pragma unroll
    for (int nt = 0; nt < 4; nt++) {
        if (nt < 2) {
            f32x4 z;
            #pragma unroll
            for (int r = 0; r < 4; r++) z[r] = fast_sigmoid(acc[nt][r]);
            *(f32x4*)&zC[((size_t)(field * TILES + tt) * 2 + nt) * 256 + lane * 4] = z;
        } else {
            int ntc = nt - 2;
            f32x4 hp = (f32x4)0.f;
            if (s > 0)
                hp = *(const f32x4*)&hC_prev[((size_t)(field * TILES + tt) * 2 + ntc) * 256 + lane * 4];
            #pragma unroll
            for (int r = 0; r < 4; r++) {
                float rv = fast_sigmoid(acc[nt][r]);
                int site_e = tt * 16 + q * 4 + r;
                rhs[(size_t)site_e * Fn + ntc * 16 + n] = f2bf(rv * hp[r]);
            }
        }
    }
}

// ---- update: candidate conv over rh + x, then h = z*h_prev + (1-z)*tanh(.) ----
__global__ __launch_bounds__(256, 3) void update_mfma(
    const short* __restrict__ xb8, const short* __restrict__ whP,
    const short* __restrict__ wxP,
    const float* __restrict__ b_f, const float* __restrict__ b_b,
    const short* __restrict__ rh,
    const float* __restrict__ hC_prev, const float* __restrict__ zC,
    float* __restrict__ hC_cur, short* __restrict__ hb_cur,
    float* __restrict__ out, int s)
{
    __shared__ short wl[32 * W_ROW];     // rows: [0,288)=Wh, [288,384)=Wx cols 64..95
    int tid = threadIdx.x;
    int bid = blockIdx.x;
    int field = bid / 150;
    int tb    = bid % 150;
    int dir = field >> 1;
    int b   = field & 1;
    int t = dir ? (Tn - 1 - s) : s;

    {
        const short* wh = whP + dir * 32 * 288;
        const short* wx = wxP + dir * 96 * 96;
        for (int i = tid; i < 32 * 48; i += 256) {
            int row = i / 48, c = i % 48;
            uint4 v = (c < 36) ? *(const uint4*)&wh[row * 288 + c * 8]
                               : *(const uint4*)&wx[(64 + row) * 96 + (c - 36) * 8];
            *(uint4*)&wl[row * W_ROW + c * 8] = v;
        }
    }
    __syncthreads();

    int wid = tid >> 6, lane = tid & 63;
    int n = lane & 15, q = lane >> 4, q8 = q * 8;
    int tt = tb * 4 + wid;
    int site = tt * 16 + n;
    int y = site / Wn, px = site % Wn;

    const short* rhs = rh + (size_t)field * SITES * Fn;
    const short* xs  = xb8 + (size_t)((b * Tn + t) * SITES) * 8;
    const float* bias = dir ? b_b : b_f;

    f32x4 acc[2];
    #pragma unroll
    for (int ntc = 0; ntc < 2; ntc++) acc[ntc] = (f32x4)(bias[64 + ntc * 16 + n]);

    // x chunks
    #pragma unroll
    for (int c = 0; c < 3; c++) {
        int tap = c * 4 + q;
        short8 a = (short8)(short)0;
        if (tap < 9) {
            int iy = y + tap / 3 - 1;
            int ix = px + tap % 3 - 1;
            if (iy >= 0 && iy < Hn && ix >= 0 && ix < Wn)
                a = *(const short8*)&xs[(size_t)(iy * Wn + ix) * 8];
        }
        #pragma unroll
        for (int ntc = 0; ntc < 2; ntc++) {
            short8 bf = *(const short8*)&wl[(ntc * 16 + n) * W_ROW + 288 + c * 32 + q8];
            acc[ntc] = __builtin_amdgcn_mfma_f32_16x16x32_bf16(a, bf, acc[ntc], 0, 0, 0);
        }
    }

    // rh chunks (rh fully written by gates every step; zeros at s==0)
    #pragma unroll
    for (int ky = 0; ky < 3; ky++) {
        int iy = y + ky - 1;
        bool rowok = (iy >= 0 && iy < Hn);
        #pragma unroll
        for (int kx = 0; kx < 3; kx++) {
            int tap = ky * 3 + kx;
            int ix = px + kx - 1;
            bool ok = rowok && ix >= 0 && ix < Wn;
            short8 ar = (short8)(short)0;
            if (ok) ar = *(const short8*)&rhs[(size_t)(iy * Wn + ix) * Fn + q8];
            #pragma unroll
            for (int ntc = 0; ntc < 2; ntc++) {
                short8 bh = *(const short8*)&wl[(ntc * 16 + n) * W_ROW + tap * 32 + q8];
                acc[ntc] = __builtin_amdgcn_mfma_f32_16x16x32_bf16(ar, bh, acc[ntc], 0, 0, 0);
            }
        }
    }

    short* hbc = hb_cur + (size_t)field * SITES * Fn;
    #pragma unroll
    for (int ntc = 0; ntc < 2; ntc++) {
        size_t cofs = ((size_t)(field * TILES + tt) * 2 + ntc) * 256 + lane * 4;
        f32x4 z  = *(const f32x4*)&zC[cofs];
        f32x4 hp = (f32x4)0.f;
        if (s > 0) hp = *(const f32x4*)&hC_prev[cofs];
        f32x4 hn;
        #pragma unroll
        for (int r = 0; r < 4; r++) {
            float hh = fast_tanh(acc[ntc][r]);
            hn[r] = z[r] * hp[r] + (1.f - z[r]) * hh;
        }
        *(f32x4*)&hC_cur[cofs] = hn;
        #pragma unroll
        for (int r = 0; r < 4; r++) {
            int site_e = tt * 16 + q * 4 + r;
            int ch = ntc * 16 + n;
            hbc[(size_t)site_e * Fn + ch] = f2bf(hn[r]);
            out[((size_t)((b * Tn + t) * SITES) + site_e) * 64 + dir * Fn + ch] = hn[r];
        }
    }
}

extern "C" void kernel_launch(void* const* d_in, const int* in_sizes, int n_in,
                              void* d_out, int out_size, void* d_ws, size_t ws_size,
                              hipStream_t stream)
{
    const float* x     = (const float*)d_in[0];
    const float* Wx_f  = (const float*)d_in[1];
    const float* b_f   = (const float*)d_in[2];
    const float* Wzr_f = (const float*)d_in[3];
    const float* Wh_f  = (const float*)d_in[4];
    const float* Wx_b  = (const float*)d_in[5];
    const float* b_b   = (const float*)d_in[6];
    const float* Wzr_b = (const float*)d_in[7];
    const float* Wh_b  = (const float*)d_in[8];
    float* out = (float*)d_out;

    char* w = (char*)d_ws;
    float*  hC0  = (float*)w;  w += (size_t)HSZ * 4;
    float*  hC1  = (float*)w;  w += (size_t)HSZ * 4;
    float*  zC   = (float*)w;  w += (size_t)HSZ * 4;
    short*  hb0  = (short*)w;  w += (size_t)HSZ * 2;
    short*  hb1  = (short*)w;  w += (size_t)HSZ * 2;
    short*  rh   = (short*)w;  w += (size_t)HSZ * 2;
    short*  xb8  = (short*)w;  w += (size_t)Bn * Tn * SITES * 8 * 2;  // 3.7 MB
    short*  wzrP = (short*)w;  w += 2 * 64 * 288 * 2;
    short*  whP  = (short*)w;  w += 2 * 32 * 288 * 2;
    short*  wxP  = (short*)w;  w += 2 * 96 * 96 * 2;
    // total ~26 MB

    // prologue: weights + x pack in one launch (304128 work items)
    prep_kernel<<<1188, 256, 0, stream>>>(Wzr_f, Wzr_b, Wh_f, Wh_b, Wx_f, Wx_b, x,
                                          wzrP, whP, wxP, xb8);

    for (int s = 0; s < Tn; s++) {
        int cur = s & 1;
        float* hCp = cur ? hC0 : hC1;
        float* hCc = cur ? hC1 : hC0;
        short* hbp = cur ? hb0 : hb1;
        short* hbc = cur ? hb1 : hb0;
        gates_mfma<<<600, 256, 0, stream>>>(xb8, wzrP, wxP, b_f, b_b,
                                            hbp, hCp, zC, rh, s);
        update_mfma<<<600, 256, 0, stream>>>(xb8, whP, wxP, b_f, b_b,
                                             rh, hCp, zC, hCc, hbc, out, s);
    }
}